// Round 13
// baseline (264.193 us; speedup 1.0000x reference)
//
#include <hip/hip_runtime.h>
#include <hip/hip_fp16.h>

#define N_NODES  500000
#define N_EDGES  16000000
#define N_GRAPHS 5000

// radix partition params
#define NBIN  512                  // buckets (dst>>10), 1024 nodes each
#define BSZN  1024                 // nodes per bucket
#define CH    8192                 // edges per chunk (pow2)
#define NCH   1954                 // ceil(16e6/8192); NCH*NBIN = 1,000,448

// fixed-point scale for LDS int accumulation
#define FXS   262144.0f            // 2^18
#define FXI   3.814697265625e-06f  // 2^-18

// workspace layout (4-byte element offsets)
#define WS_AGG     0               // int32 fixed-point agg, N*4 = 2,000,000
#define WS_SUMS    2000000         // float, G*64  = 320,000
#define WS_CNT     2320000         // float, G     = 5,000
#define WS_W1F     2325008         // float, 512   (w1 folded, [j][c])
#define WS_B1F     2325520         // float, 128
#define WS_W2F     2325648         // 8192 dw; w2T bf16 [64][128] (4096 dw used)
#define WS_B2F     2333840         // float, 64
#define WS_HIST    2333904         // int, NCH*NBIN = 1,000,448 [chunk][bin]; XH overlay after e3
#define WS_XH      WS_HIST
#define WS_BTOT    3334352         // int, NBIN
#define WS_BSTART  3334864         // int, NBIN+1
#define WS_CSR     3335380         // uint, 16,000,000  (16B aligned for uint4 loads)
#define WS_TOTAL_ELEMS 19335380

typedef __attribute__((ext_vector_type(8))) short short8;
typedef __attribute__((ext_vector_type(4))) float f32x4;
typedef __attribute__((ext_vector_type(4))) unsigned int u32x4;

static __device__ __forceinline__ unsigned short bf16r(float f) {
    unsigned int u = __float_as_uint(f);
    u = u + 0x7FFFu + ((u >> 16) & 1u);   // round-to-nearest-even
    return (unsigned short)(u >> 16);
}

// ---------------- fold BN into weights (w2 -> transposed bf16) ----------------
__global__ void k_prep(const float* __restrict__ w1, const float* __restrict__ b1,
                       const float* __restrict__ g1, const float* __restrict__ be1,
                       const float* __restrict__ m1, const float* __restrict__ v1,
                       const float* __restrict__ w2, const float* __restrict__ b2,
                       const float* __restrict__ g2, const float* __restrict__ be2,
                       const float* __restrict__ m2, const float* __restrict__ v2,
                       float* __restrict__ ws) {
    int t = threadIdx.x;  // 128 threads
    if (t < 128) {
        float s = g1[t] * rsqrtf(v1[t] + 1e-5f);
        ws[WS_B1F + t] = (b1[t] - m1[t]) * s + be1[t];
        for (int c = 0; c < 4; ++c)
            ws[WS_W1F + t * 4 + c] = w1[c * 128 + t] * s;   // [j][c]
    }
    if (t < 64) {
        float s = g2[t] * rsqrtf(v2[t] + 1e-5f);
        ws[WS_B2F + t] = (b2[t] - m2[t]) * s + be2[t];
        unsigned short* w2t = (unsigned short*)(ws + WS_W2F);  // [kout][j] bf16
        for (int j = 0; j < 128; ++j)
            w2t[t * 128 + j] = bf16r(w2[j * 64 + t] * s);
    }
}

// ---------------- x -> fp16x4 table (after e3; overlays dead hist) ----------------
__global__ __launch_bounds__(256) void k_xhalf(const float4* __restrict__ x4,
                                               uint2* __restrict__ xh) {
    int i = blockIdx.x * 256 + threadIdx.x;
    if (i >= N_NODES) return;
    float4 v = x4[i];
    __half2 a = __floats2half2_rn(v.x, v.y);
    __half2 b = __floats2half2_rn(v.z, v.w);
    uint2 p;
    p.x = *(unsigned int*)&a;
    p.y = *(unsigned int*)&b;
    xh[i] = p;
}

// ---------------- E1: per-chunk bucket histogram (int4 reads) ----------------
__global__ __launch_bounds__(256) void k_e1_hist(const int* __restrict__ ei,
                                                 int* __restrict__ hist) {
    __shared__ int h[NBIN];
    int t = threadIdx.x, blk = blockIdx.x;
    for (int i = t; i < NBIN; i += 256) h[i] = 0;
    __syncthreads();
    int base = blk * CH;
    int nE = min(CH, N_EDGES - base);     // always multiple of 4
    const int4* d4 = (const int4*)(ei + N_EDGES + base);
    for (int i = t; i < (nE >> 2); i += 256) {
        int4 d = d4[i];
        atomicAdd(&h[d.x >> 10], 1);
        atomicAdd(&h[d.y >> 10], 1);
        atomicAdd(&h[d.z >> 10], 1);
        atomicAdd(&h[d.w >> 10], 1);
    }
    __syncthreads();
    for (int i = t; i < NBIN; i += 256) hist[blk * NBIN + i] = h[i];
}

// ---------------- E2a: per-bin exclusive scan over 1954 chunks (parallel) ----------------
__global__ __launch_bounds__(256) void k_e2a_scan(int* __restrict__ hist,
                                                  int* __restrict__ binTotal) {
    __shared__ int buf[2048];
    __shared__ int wsum[4], woff2[4];
    int t = threadIdx.x, bin = blockIdx.x;
    for (int i = t; i < 2048; i += 256)
        buf[i] = (i < NCH) ? hist[i * NBIN + bin] : 0;
    __syncthreads();
    int s = 0;
    #pragma unroll
    for (int k = 0; k < 8; ++k) s += buf[t * 8 + k];
    int inc = s;
    #pragma unroll
    for (int dlt = 1; dlt < 64; dlt <<= 1) {
        int n = __shfl_up(inc, dlt, 64);
        if ((t & 63) >= dlt) inc += n;
    }
    if ((t & 63) == 63) wsum[t >> 6] = inc;
    __syncthreads();
    if (t == 0) { int r = 0; for (int w = 0; w < 4; ++w) { woff2[w] = r; r += wsum[w]; } }
    __syncthreads();
    int run = inc - s + woff2[t >> 6];
    #pragma unroll
    for (int k = 0; k < 8; ++k) { int v = buf[t * 8 + k]; buf[t * 8 + k] = run; run += v; }
    __syncthreads();
    if (t == 0) binTotal[bin] = woff2[3] + wsum[3];
    for (int i = t; i < NCH; i += 256) hist[i * NBIN + bin] = buf[i];
}

// ---------------- E2b: scan 512 bin totals -> bucket starts ----------------
__global__ __launch_bounds__(512) void k_e2b_scan(const int* __restrict__ binTotal,
                                                  int* __restrict__ binStart) {
    __shared__ int wtot[8], woff[8];
    int t = threadIdx.x;
    int v = binTotal[t];
    int inc = v;
    #pragma unroll
    for (int dlt = 1; dlt < 64; dlt <<= 1) {
        int n = __shfl_up(inc, dlt, 64);
        if ((t & 63) >= dlt) inc += n;
    }
    if ((t & 63) == 63) wtot[t >> 6] = inc;
    __syncthreads();
    if (t == 0) { int r = 0; for (int w = 0; w < 8; ++w) { woff[w] = r; r += wtot[w]; } }
    __syncthreads();
    int excl = inc - v + woff[t >> 6];
    binStart[t] = excl;
    if (t == NBIN - 1) binStart[NBIN] = excl + v;   // == N_EDGES
}

// ---------------- E3: counting sort per chunk; counts recovered from scanned hist ----------------
#define E3T 512
__global__ __launch_bounds__(E3T) void k_e3_sort(const int* __restrict__ ei,
                                                 const int* __restrict__ hist,
                                                 const int* __restrict__ binTotal,
                                                 const int* __restrict__ binStart,
                                                 unsigned int* __restrict__ csr) {
    __shared__ unsigned int ebuf[CH];   // 32 KB
    __shared__ int lhist[NBIN];
    __shared__ int gbase[NBIN];
    __shared__ int cursor[NBIN];
    __shared__ int wtot[8], woff[8];
    int t = threadIdx.x, c = blockIdx.x;

    int base = c * CH;
    int nE = min(CH, N_EDGES - base);

    // counts from scanned hist: count = next_prefix - cur_prefix
    int histcur  = hist[c * NBIN + t];
    int histnext = (c < NCH - 1) ? hist[(c + 1) * NBIN + t] : binTotal[t];
    int v = histnext - histcur;
    lhist[t] = v;
    // 3-barrier shfl exclusive scan over 512 bins
    int inc = v;
    #pragma unroll
    for (int dlt = 1; dlt < 64; dlt <<= 1) {
        int n = __shfl_up(inc, dlt, 64);
        if ((t & 63) >= dlt) inc += n;
    }
    if ((t & 63) == 63) wtot[t >> 6] = inc;
    __syncthreads();
    if (t == 0) { int r = 0; for (int w = 0; w < 8; ++w) { woff[w] = r; r += wtot[w]; } }
    __syncthreads();
    int excl = inc - v + woff[t >> 6];
    cursor[t] = excl;
    gbase[t]  = binStart[t] + histcur;
    __syncthreads();
    // place into LDS sorted by bin (int4 source reads)
    {
        const int4* s4 = (const int4*)(ei + base);
        const int4* d4 = (const int4*)(ei + N_EDGES + base);
        for (int i = t; i < (nE >> 2); i += E3T) {
            int4 s = s4[i];
            int4 d = d4[i];
            int p0 = atomicAdd(&cursor[d.x >> 10], 1);
            ebuf[p0] = ((unsigned int)s.x << 10) | (unsigned int)(d.x & 1023);
            int p1 = atomicAdd(&cursor[d.y >> 10], 1);
            ebuf[p1] = ((unsigned int)s.y << 10) | (unsigned int)(d.y & 1023);
            int p2 = atomicAdd(&cursor[d.z >> 10], 1);
            ebuf[p2] = ((unsigned int)s.z << 10) | (unsigned int)(d.z & 1023);
            int p3 = atomicAdd(&cursor[d.w >> 10], 1);
            ebuf[p3] = ((unsigned int)s.w << 10) | (unsigned int)(d.w & 1023);
        }
    }
    __syncthreads();
    // coalesced writeout, 16-lane group per bin run (avg run ~16)
    int grp = t >> 4, lane = t & 15;
    for (int b = grp; b < NBIN; b += (E3T / 16)) {
        int n  = lhist[b];
        int lb = cursor[b] - n;         // run start in ebuf (cursor = excl + n now)
        int gb = gbase[b];
        for (int j = lane; j < n; j += 16)
            csr[gb + j] = ebuf[lb + j];
    }
}

// ---------------- E4: full-bin blocks, u32x4 csr loads (unroll 4), fixed-point LDS atomics ----------------
__global__ __launch_bounds__(1024) void k_e4_agg(const unsigned int* __restrict__ csr,
                                                 const int* __restrict__ binStart,
                                                 const uint2* __restrict__ xh,
                                                 int* __restrict__ aggi) {
    __shared__ int aggs_i[BSZN * 4];   // 16 KB, [c][loc] plane layout
    int t = threadIdx.x, bin = blockIdx.x;
    for (int i = t; i < BSZN * 4; i += 1024) aggs_i[i] = 0;
    __syncthreads();
    int start = binStart[bin];
    int end   = binStart[bin + 1];

#define E4_PROC(vv) {                                              \
        unsigned int v_ = (vv);                                    \
        int src_ = (int)(v_ >> 10);                                \
        int loc_ = (int)(v_ & 1023u);                              \
        uint2 p_ = xh[src_];                                       \
        __half2 ab_ = *(__half2*)&p_.x;                            \
        __half2 cd_ = *(__half2*)&p_.y;                            \
        float2 f0_ = __half22float2(ab_);                          \
        float2 f1_ = __half22float2(cd_);                          \
        atomicAdd(&aggs_i[0 * BSZN + loc_], __float2int_rn(f0_.x * FXS)); \
        atomicAdd(&aggs_i[1 * BSZN + loc_], __float2int_rn(f0_.y * FXS)); \
        atomicAdd(&aggs_i[2 * BSZN + loc_], __float2int_rn(f1_.x * FXS)); \
        atomicAdd(&aggs_i[3 * BSZN + loc_], __float2int_rn(f1_.y * FXS)); \
    }

    // peel to 16B alignment: head [start,as), vector [as,ae), tail [ae,end)
    int as = (start + 3) & ~3; if (as > end) as = end;
    int ae = end & ~3;         if (ae < as)  ae = as;
    if (t < (as - start)) E4_PROC(csr[start + t]);
    if (t < (end - ae))   E4_PROC(csr[ae + t]);
    const u32x4* c4 = (const u32x4*)csr;   // csr base 16B aligned
    #pragma unroll 4
    for (int i = (as >> 2) + t; i < (ae >> 2); i += 1024) {
        u32x4 v = __builtin_nontemporal_load(&c4[i]);
        E4_PROC(v.x); E4_PROC(v.y); E4_PROC(v.z); E4_PROC(v.w);
    }
#undef E4_PROC

    __syncthreads();
    int nodeBase = bin * BSZN;
    if (nodeBase >= N_NODES) return;
    int nv = min(BSZN, N_NODES - nodeBase) * 4;
    for (int i = t; i < nv; i += 1024)
        aggi[nodeBase * 4 + i] = aggs_i[(i & 3) * BSZN + (i >> 2)];
}

// ---------------- fallback edge scatter (if ws too small): float agg in CSR region ----------------
__global__ __launch_bounds__(256) void k_edge(const int* __restrict__ ei,
                                              const float4* __restrict__ x4,
                                              float* __restrict__ aggf) {
    int e = blockIdx.x * 256 + threadIdx.x;
    if (e >= N_EDGES) return;
    int s = ei[e];
    int d = ei[N_EDGES + e];
    float4 v = x4[s];
    atomicAdd(&aggf[d * 4 + 0], v.x);
    atomicAdd(&aggf[d * 4 + 1], v.y);
    atomicAdd(&aggf[d * 4 + 2], v.z);
    atomicAdd(&aggf[d * 4 + 3], v.w);
}

// ---------------- node MLP via MFMA (w2 register-resident) + pooling ----------------
__global__ __launch_bounds__(512) void k_node(const float4* __restrict__ x4,
                                              const uint2* __restrict__ xh,
                                              const int* __restrict__ aggi,
                                              const float* __restrict__ aggf,
                                              int useFix,
                                              const int* __restrict__ batch,
                                              const float* __restrict__ epsp,
                                              const float* __restrict__ ws,
                                              float* __restrict__ sums,
                                              float* __restrict__ cnt) {
    __shared__ float w1s4[4 * 516];      // 4 bank-offset replicas of w1 [j][c]
    __shared__ float b1s[128];
    __shared__ float b2s[64];
    __shared__ float h2t[8][16][68];     // per-wave h2 tile (slow path only)
    __shared__ int   bshW[128];

    int tid  = threadIdx.x;
    int wave = tid >> 6;
    int l    = tid & 63;
    int cl   = l & 15;
    int q8   = l >> 4;

    for (int i = tid; i < 2048; i += 512)
        w1s4[(i >> 9) * 516 + (i & 511)] = ws[WS_W1F + (i & 511)];
    if (tid < 128) b1s[tid] = ws[WS_B1F + tid];
    if (tid < 64)  b2s[tid] = ws[WS_B2F + tid];

    const unsigned short* w2t = (const unsigned short*)(ws + WS_W2F);
    short8 bfr[4][4];
    #pragma unroll
    for (int nt = 0; nt < 4; ++nt)
        #pragma unroll
        for (int ks = 0; ks < 4; ++ks)
            bfr[nt][ks] = *(const short8*)(w2t + (nt * 16 + cl) * 128 + ks * 32 + q8 * 8);

    __syncthreads();

    int tilebase = blockIdx.x * 128 + wave * 16;
    int node = tilebase + cl;
    bool valid = node < N_NODES;
    float4 xi = make_float4(0.f, 0.f, 0.f, 0.f);
    float4 ai = make_float4(0.f, 0.f, 0.f, 0.f);
    if (valid) {
        if (useFix) {
            uint2 p = xh[node];
            __half2 ab = *(__half2*)&p.x;
            __half2 cd = *(__half2*)&p.y;
            float2 f0 = __half22float2(ab);
            float2 f1 = __half22float2(cd);
            xi = make_float4(f0.x, f0.y, f1.x, f1.y);
            int4 av = ((const int4*)aggi)[node];
            ai = make_float4(av.x * FXI, av.y * FXI, av.z * FXI, av.w * FXI);
        } else {
            xi = x4[node];
            ai = ((const float4*)aggf)[node];
        }
    }
    int bn = valid ? batch[node] : -1;
    if (l < 16) bshW[wave * 16 + l] = bn;
    float ep = 1.0f + epsp[0];
    float hx = ep * xi.x + ai.x;
    float hy = ep * xi.y + ai.y;
    float hz = ep * xi.z + ai.z;
    float hw = ep * xi.w + ai.w;

    f32x4 acc[4];
    #pragma unroll
    for (int nt = 0; nt < 4; ++nt) acc[nt] = (f32x4){0.f, 0.f, 0.f, 0.f};

    #pragma unroll
    for (int ks = 0; ks < 4; ++ks) {
        float h1v[8];
        #pragma unroll
        for (int e = 0; e < 8; ++e) {
            int j = ks * 32 + q8 * 8 + e;
            const float4 wr = *(const float4*)&w1s4[q8 * 516 + j * 4];
            float h1 = fmaf(hx, wr.x, fmaf(hy, wr.y, fmaf(hz, wr.z, fmaf(hw, wr.w, b1s[j]))));
            h1v[e] = fmaxf(h1, 0.0f);
        }
        unsigned int aw[4];
        #pragma unroll
        for (int p2 = 0; p2 < 4; ++p2)
            asm("v_cvt_pk_bf16_f32 %0, %1, %2"
                : "=v"(aw[p2]) : "v"(h1v[2 * p2]), "v"(h1v[2 * p2 + 1]));
        short8 afrag = *(short8*)aw;
        #pragma unroll
        for (int nt = 0; nt < 4; ++nt)
            acc[nt] = __builtin_amdgcn_mfma_f32_16x16x32_bf16(afrag, bfr[nt][ks], acc[nt], 0, 0, 0);
    }

    float h2v[4][4];
    #pragma unroll
    for (int nt = 0; nt < 4; ++nt) {
        float b2v = b2s[nt * 16 + cl];
        #pragma unroll
        for (int r = 0; r < 4; ++r)
            h2v[nt][r] = fmaxf(acc[nt][r] + b2v, 0.0f);
    }

    int firstb = __shfl(bn, 0);
    bool uni = __all(bn == firstb) && (firstb >= 0);
    if (uni) {
        float s[4];
        #pragma unroll
        for (int nt = 0; nt < 4; ++nt) {
            float v = h2v[nt][0] + h2v[nt][1] + h2v[nt][2] + h2v[nt][3];
            v += __shfl_xor(v, 16);
            v += __shfl_xor(v, 32);
            s[nt] = v;
        }
        if (l < 16) {
            #pragma unroll
            for (int nt = 0; nt < 4; ++nt)
                atomicAdd(&sums[firstb * 64 + nt * 16 + l], s[nt]);
        }
        if (l == 0) atomicAdd(&cnt[firstb], 16.0f);
    } else {
        #pragma unroll
        for (int nt = 0; nt < 4; ++nt)
            #pragma unroll
            for (int r = 0; r < 4; ++r)
                h2t[wave][q8 * 4 + r][nt * 16 + cl] = h2v[nt][r];
        int kout = l;   // 0..63
        float a = 0.f, c = 0.f;
        int cur = -1;
        for (int n = 0; n < 16; ++n) {
            int bn2 = bshW[wave * 16 + n];
            if (bn2 != cur) {
                if (cur >= 0) {
                    atomicAdd(&sums[cur * 64 + kout], a);
                    if (l == 0) atomicAdd(&cnt[cur], c);
                }
                a = 0.f; c = 0.f; cur = bn2;
            }
            if (bn2 >= 0) { a += h2t[wave][n][kout]; c += 1.f; }
        }
        if (cur >= 0) {
            atomicAdd(&sums[cur * 64 + kout], a);
            if (l == 0) atomicAdd(&cnt[cur], c);
        }
    }
}

// ---------------- head ----------------
__global__ __launch_bounds__(256) void k_head(const float* __restrict__ sums,
                                              const float* __restrict__ cnt,
                                              const float* __restrict__ w3,
                                              const float* __restrict__ b3,
                                              float* __restrict__ out) {
    int g = blockIdx.x * 256 + threadIdx.x;
    if (g >= N_GRAPHS) return;
    float ic = 1.0f / fmaxf(cnt[g], 1.0f);
    float l0 = b3[0], l1 = b3[1];
    #pragma unroll 8
    for (int k = 0; k < 64; ++k) {
        float p = sums[g * 64 + k] * ic;
        l0 = fmaf(p, w3[k * 2 + 0], l0);
        l1 = fmaf(p, w3[k * 2 + 1], l1);
    }
    float m = fmaxf(l0, l1);
    float lse = m + logf(expf(l0 - m) + expf(l1 - m));
    out[g * 2 + 0] = l0 - lse;
    out[g * 2 + 1] = l1 - lse;
}

extern "C" void kernel_launch(void* const* d_in, const int* in_sizes, int n_in,
                              void* d_out, int out_size, void* d_ws, size_t ws_size,
                              hipStream_t stream) {
    const float* x   = (const float*)d_in[0];
    const float* eps = (const float*)d_in[1];
    const float* w1  = (const float*)d_in[2];
    const float* b1  = (const float*)d_in[3];
    const float* g1  = (const float*)d_in[4];
    const float* be1 = (const float*)d_in[5];
    const float* m1  = (const float*)d_in[6];
    const float* v1  = (const float*)d_in[7];
    const float* w2  = (const float*)d_in[8];
    const float* b2  = (const float*)d_in[9];
    const float* g2  = (const float*)d_in[10];
    const float* be2 = (const float*)d_in[11];
    const float* m2  = (const float*)d_in[12];
    const float* v2  = (const float*)d_in[13];
    const float* w3  = (const float*)d_in[14];
    const float* b3  = (const float*)d_in[15];
    const int*   ei  = (const int*)d_in[16];
    const int*   batch = (const int*)d_in[17];

    float* ws = (float*)d_ws;
    int*   wsi = (int*)d_ws;

    k_prep<<<1, 128, 0, stream>>>(w1, b1, g1, be1, m1, v1, w2, b2, g2, be2, m2, v2, ws);

    if (ws_size >= (size_t)WS_TOTAL_ELEMS * 4) {
        // zero only sums + cnt (agg fully stored by e4)
        (void)hipMemsetAsync(ws + WS_SUMS, 0, (size_t)325000 * sizeof(float), stream);

        k_e1_hist<<<NCH, 256, 0, stream>>>(ei, wsi + WS_HIST);
        k_e2a_scan<<<NBIN, 256, 0, stream>>>(wsi + WS_HIST, wsi + WS_BTOT);
        k_e2b_scan<<<1, NBIN, 0, stream>>>(wsi + WS_BTOT, wsi + WS_BSTART);
        k_e3_sort<<<NCH, E3T, 0, stream>>>(ei, wsi + WS_HIST, wsi + WS_BTOT,
                                           wsi + WS_BSTART,
                                           (unsigned int*)(wsi + WS_CSR));
        // hist is dead now -> overlay fp16 x table
        k_xhalf<<<(N_NODES + 255) / 256, 256, 0, stream>>>((const float4*)x,
                                                           (uint2*)(wsi + WS_XH));
        k_e4_agg<<<NBIN, 1024, 0, stream>>>((const unsigned int*)(wsi + WS_CSR),
                                            wsi + WS_BSTART,
                                            (const uint2*)(wsi + WS_XH),
                                            wsi + WS_AGG);
        k_node<<<(N_NODES + 127) / 128, 512, 0, stream>>>(
            (const float4*)x, (const uint2*)(wsi + WS_XH), wsi + WS_AGG,
            (const float*)nullptr, 1, batch, eps, ws,
            ws + WS_SUMS, ws + WS_CNT);
    } else {
        // fallback: global-atomic scatter into float agg placed in CSR region
        (void)hipMemsetAsync(ws + WS_SUMS, 0, (size_t)325000 * sizeof(float), stream);
        (void)hipMemsetAsync(ws + WS_CSR, 0, (size_t)2000000 * sizeof(float), stream);
        k_edge<<<(N_EDGES + 255) / 256, 256, 0, stream>>>(ei, (const float4*)x,
                                                          ws + WS_CSR);
        k_node<<<(N_NODES + 127) / 128, 512, 0, stream>>>(
            (const float4*)x, (const uint2*)nullptr, (const int*)nullptr,
            ws + WS_CSR, 0, batch, eps, ws,
            ws + WS_SUMS, ws + WS_CNT);
    }

    k_head<<<(N_GRAPHS + 255) / 256, 256, 0, stream>>>(
        ws + WS_SUMS, ws + WS_CNT, w3, b3, (float*)d_out);
}

// Round 14
// 247.344 us; speedup vs baseline: 1.0681x; 1.0681x over previous
//
#include <hip/hip_runtime.h>
#include <hip/hip_fp16.h>

#define N_NODES  500000
#define N_EDGES  16000000
#define N_GRAPHS 5000

// radix partition params
#define NBIN  512                  // buckets (dst>>10), 1024 nodes each
#define BSZN  1024                 // nodes per bucket
#define CH    16384                // edges per chunk (pow2)
#define NCH   977                  // ceil(16e6/16384); last chunk 9216 edges

// fixed-point scale for LDS int accumulation
#define FXS   262144.0f            // 2^18
#define FXI   3.814697265625e-06f  // 2^-18

// workspace layout (4-byte element offsets)
#define WS_AGG     0               // int32 fixed-point agg, N*4 = 2,000,000
#define WS_SUMS    2000000         // float, G*64  = 320,000
#define WS_CNT     2320000         // float, G     = 5,000
#define WS_W1F     2325008         // float, 512   (w1 folded, [j][c])
#define WS_B1F     2325520         // float, 128
#define WS_W2F     2325648         // 8192 dw; w2T bf16 [64][128] (4096 dw used)
#define WS_B2F     2333840         // float, 64
#define WS_HIST    2333904         // int, NCH*NBIN = 500,224; region reserved 1,000,448 (XH overlay)
#define WS_XH      WS_HIST
#define WS_BTOT    3334352         // int, NBIN
#define WS_BSTART  3334864         // int, NBIN+1
#define WS_CSR     3335380         // uint, 16,000,000  (16B aligned for uint4 loads)
#define WS_TOTAL_ELEMS 19335380

typedef __attribute__((ext_vector_type(8))) short short8;
typedef __attribute__((ext_vector_type(4))) float f32x4;
typedef __attribute__((ext_vector_type(4))) unsigned int u32x4;

static __device__ __forceinline__ unsigned short bf16r(float f) {
    unsigned int u = __float_as_uint(f);
    u = u + 0x7FFFu + ((u >> 16) & 1u);   // round-to-nearest-even
    return (unsigned short)(u >> 16);
}

// ---------------- fold BN into weights (w2 -> transposed bf16) ----------------
__global__ void k_prep(const float* __restrict__ w1, const float* __restrict__ b1,
                       const float* __restrict__ g1, const float* __restrict__ be1,
                       const float* __restrict__ m1, const float* __restrict__ v1,
                       const float* __restrict__ w2, const float* __restrict__ b2,
                       const float* __restrict__ g2, const float* __restrict__ be2,
                       const float* __restrict__ m2, const float* __restrict__ v2,
                       float* __restrict__ ws) {
    int t = threadIdx.x;  // 128 threads
    if (t < 128) {
        float s = g1[t] * rsqrtf(v1[t] + 1e-5f);
        ws[WS_B1F + t] = (b1[t] - m1[t]) * s + be1[t];
        for (int c = 0; c < 4; ++c)
            ws[WS_W1F + t * 4 + c] = w1[c * 128 + t] * s;   // [j][c]
    }
    if (t < 64) {
        float s = g2[t] * rsqrtf(v2[t] + 1e-5f);
        ws[WS_B2F + t] = (b2[t] - m2[t]) * s + be2[t];
        unsigned short* w2t = (unsigned short*)(ws + WS_W2F);  // [kout][j] bf16
        for (int j = 0; j < 128; ++j)
            w2t[t * 128 + j] = bf16r(w2[j * 64 + t] * s);
    }
}

// ---------------- x -> fp16x4 table (after e3; overlays dead hist) ----------------
__global__ __launch_bounds__(256) void k_xhalf(const float4* __restrict__ x4,
                                               uint2* __restrict__ xh) {
    int i = blockIdx.x * 256 + threadIdx.x;
    if (i >= N_NODES) return;
    float4 v = x4[i];
    __half2 a = __floats2half2_rn(v.x, v.y);
    __half2 b = __floats2half2_rn(v.z, v.w);
    uint2 p;
    p.x = *(unsigned int*)&a;
    p.y = *(unsigned int*)&b;
    xh[i] = p;
}

// ---------------- E1: per-chunk bucket histogram (int4 reads) ----------------
__global__ __launch_bounds__(256) void k_e1_hist(const int* __restrict__ ei,
                                                 int* __restrict__ hist) {
    __shared__ int h[NBIN];
    int t = threadIdx.x, blk = blockIdx.x;
    for (int i = t; i < NBIN; i += 256) h[i] = 0;
    __syncthreads();
    int base = blk * CH;
    int nE = min(CH, N_EDGES - base);     // always multiple of 4
    const int4* d4 = (const int4*)(ei + N_EDGES + base);
    for (int i = t; i < (nE >> 2); i += 256) {
        int4 d = d4[i];
        atomicAdd(&h[d.x >> 10], 1);
        atomicAdd(&h[d.y >> 10], 1);
        atomicAdd(&h[d.z >> 10], 1);
        atomicAdd(&h[d.w >> 10], 1);
    }
    __syncthreads();
    for (int i = t; i < NBIN; i += 256) hist[blk * NBIN + i] = h[i];
}

// ---------------- E2a: per-bin exclusive scan over 977 chunks (parallel) ----------------
__global__ __launch_bounds__(256) void k_e2a_scan(int* __restrict__ hist,
                                                  int* __restrict__ binTotal) {
    __shared__ int buf[1024];
    __shared__ int wsum[4], woff2[4];
    int t = threadIdx.x, bin = blockIdx.x;
    for (int i = t; i < 1024; i += 256)
        buf[i] = (i < NCH) ? hist[i * NBIN + bin] : 0;
    __syncthreads();
    int s = 0;
    #pragma unroll
    for (int k = 0; k < 4; ++k) s += buf[t * 4 + k];
    int inc = s;
    #pragma unroll
    for (int dlt = 1; dlt < 64; dlt <<= 1) {
        int n = __shfl_up(inc, dlt, 64);
        if ((t & 63) >= dlt) inc += n;
    }
    if ((t & 63) == 63) wsum[t >> 6] = inc;
    __syncthreads();
    if (t == 0) { int r = 0; for (int w = 0; w < 4; ++w) { woff2[w] = r; r += wsum[w]; } }
    __syncthreads();
    int run = inc - s + woff2[t >> 6];
    #pragma unroll
    for (int k = 0; k < 4; ++k) { int v = buf[t * 4 + k]; buf[t * 4 + k] = run; run += v; }
    __syncthreads();
    if (t == 0) binTotal[bin] = woff2[3] + wsum[3];
    for (int i = t; i < NCH; i += 256) hist[i * NBIN + bin] = buf[i];
}

// ---------------- E2b: scan 512 bin totals -> bucket starts ----------------
__global__ __launch_bounds__(512) void k_e2b_scan(const int* __restrict__ binTotal,
                                                  int* __restrict__ binStart) {
    __shared__ int wtot[8], woff[8];
    int t = threadIdx.x;
    int v = binTotal[t];
    int inc = v;
    #pragma unroll
    for (int dlt = 1; dlt < 64; dlt <<= 1) {
        int n = __shfl_up(inc, dlt, 64);
        if ((t & 63) >= dlt) inc += n;
    }
    if ((t & 63) == 63) wtot[t >> 6] = inc;
    __syncthreads();
    if (t == 0) { int r = 0; for (int w = 0; w < 8; ++w) { woff[w] = r; r += wtot[w]; } }
    __syncthreads();
    int excl = inc - v + woff[t >> 6];
    binStart[t] = excl;
    if (t == NBIN - 1) binStart[NBIN] = excl + v;   // == N_EDGES
}

// ---------------- E3: counting sort per chunk; counts recovered from scanned hist ----------------
#define E3T 512
__global__ __launch_bounds__(E3T) void k_e3_sort(const int* __restrict__ ei,
                                                 const int* __restrict__ hist,
                                                 const int* __restrict__ binTotal,
                                                 const int* __restrict__ binStart,
                                                 unsigned int* __restrict__ csr) {
    __shared__ unsigned int ebuf[CH];   // 64 KB
    __shared__ int lhist[NBIN];
    __shared__ int gbase[NBIN];
    __shared__ int cursor[NBIN];
    __shared__ int wtot[8], woff[8];
    int t = threadIdx.x, c = blockIdx.x;

    int base = c * CH;
    int nE = min(CH, N_EDGES - base);

    // counts from scanned hist: count = next_prefix - cur_prefix
    int histcur  = hist[c * NBIN + t];
    int histnext = (c < NCH - 1) ? hist[(c + 1) * NBIN + t] : binTotal[t];
    int v = histnext - histcur;
    lhist[t] = v;
    // 3-barrier shfl exclusive scan over 512 bins
    int inc = v;
    #pragma unroll
    for (int dlt = 1; dlt < 64; dlt <<= 1) {
        int n = __shfl_up(inc, dlt, 64);
        if ((t & 63) >= dlt) inc += n;
    }
    if ((t & 63) == 63) wtot[t >> 6] = inc;
    __syncthreads();
    if (t == 0) { int r = 0; for (int w = 0; w < 8; ++w) { woff[w] = r; r += wtot[w]; } }
    __syncthreads();
    int excl = inc - v + woff[t >> 6];
    cursor[t] = excl;
    gbase[t]  = binStart[t] + histcur;
    __syncthreads();
    // place into LDS sorted by bin (int4 source reads)
    {
        const int4* s4 = (const int4*)(ei + base);
        const int4* d4 = (const int4*)(ei + N_EDGES + base);
        for (int i = t; i < (nE >> 2); i += E3T) {
            int4 s = s4[i];
            int4 d = d4[i];
            int p0 = atomicAdd(&cursor[d.x >> 10], 1);
            ebuf[p0] = ((unsigned int)s.x << 10) | (unsigned int)(d.x & 1023);
            int p1 = atomicAdd(&cursor[d.y >> 10], 1);
            ebuf[p1] = ((unsigned int)s.y << 10) | (unsigned int)(d.y & 1023);
            int p2 = atomicAdd(&cursor[d.z >> 10], 1);
            ebuf[p2] = ((unsigned int)s.z << 10) | (unsigned int)(d.z & 1023);
            int p3 = atomicAdd(&cursor[d.w >> 10], 1);
            ebuf[p3] = ((unsigned int)s.w << 10) | (unsigned int)(d.w & 1023);
        }
    }
    __syncthreads();
    // coalesced writeout, 32-lane group per bin run (avg run ~32)
    int grp = t >> 5, lane = t & 31;
    for (int b = grp; b < NBIN; b += (E3T / 32)) {
        int n  = lhist[b];
        int lb = cursor[b] - n;         // run start in ebuf (cursor = excl + n now)
        int gb = gbase[b];
        for (int j = lane; j < n; j += 32)
            csr[gb + j] = ebuf[lb + j];
    }
}

// ---------------- E4: full-bin blocks, u32x4 csr loads, fixed-point LDS atomics ----------------
__global__ __launch_bounds__(1024) void k_e4_agg(const unsigned int* __restrict__ csr,
                                                 const int* __restrict__ binStart,
                                                 const uint2* __restrict__ xh,
                                                 int* __restrict__ aggi) {
    __shared__ int aggs_i[BSZN * 4];   // 16 KB, [c][loc] plane layout
    int t = threadIdx.x, bin = blockIdx.x;
    for (int i = t; i < BSZN * 4; i += 1024) aggs_i[i] = 0;
    __syncthreads();
    int start = binStart[bin];
    int end   = binStart[bin + 1];

#define E4_PROC(vv) {                                              \
        unsigned int v_ = (vv);                                    \
        int src_ = (int)(v_ >> 10);                                \
        int loc_ = (int)(v_ & 1023u);                              \
        uint2 p_ = xh[src_];                                       \
        __half2 ab_ = *(__half2*)&p_.x;                            \
        __half2 cd_ = *(__half2*)&p_.y;                            \
        float2 f0_ = __half22float2(ab_);                          \
        float2 f1_ = __half22float2(cd_);                          \
        atomicAdd(&aggs_i[0 * BSZN + loc_], __float2int_rn(f0_.x * FXS)); \
        atomicAdd(&aggs_i[1 * BSZN + loc_], __float2int_rn(f0_.y * FXS)); \
        atomicAdd(&aggs_i[2 * BSZN + loc_], __float2int_rn(f1_.x * FXS)); \
        atomicAdd(&aggs_i[3 * BSZN + loc_], __float2int_rn(f1_.y * FXS)); \
    }

    // peel to 16B alignment: head [start,as), vector [as,ae), tail [ae,end)
    int as = (start + 3) & ~3; if (as > end) as = end;
    int ae = end & ~3;         if (ae < as)  ae = as;
    if (t < (as - start)) E4_PROC(csr[start + t]);
    if (t < (end - ae))   E4_PROC(csr[ae + t]);
    const u32x4* c4 = (const u32x4*)csr;   // csr base 16B aligned
    for (int i = (as >> 2) + t; i < (ae >> 2); i += 1024) {
        u32x4 v = __builtin_nontemporal_load(&c4[i]);
        E4_PROC(v.x); E4_PROC(v.y); E4_PROC(v.z); E4_PROC(v.w);
    }
#undef E4_PROC

    __syncthreads();
    int nodeBase = bin * BSZN;
    if (nodeBase >= N_NODES) return;
    int nv = min(BSZN, N_NODES - nodeBase) * 4;
    for (int i = t; i < nv; i += 1024)
        aggi[nodeBase * 4 + i] = aggs_i[(i & 3) * BSZN + (i >> 2)];
}

// ---------------- fallback edge scatter (if ws too small): float agg in CSR region ----------------
__global__ __launch_bounds__(256) void k_edge(const int* __restrict__ ei,
                                              const float4* __restrict__ x4,
                                              float* __restrict__ aggf) {
    int e = blockIdx.x * 256 + threadIdx.x;
    if (e >= N_EDGES) return;
    int s = ei[e];
    int d = ei[N_EDGES + e];
    float4 v = x4[s];
    atomicAdd(&aggf[d * 4 + 0], v.x);
    atomicAdd(&aggf[d * 4 + 1], v.y);
    atomicAdd(&aggf[d * 4 + 2], v.z);
    atomicAdd(&aggf[d * 4 + 3], v.w);
}

// ---------------- node MLP via MFMA (w2 register-resident), 256 nodes/block ----------------
__global__ __launch_bounds__(512) void k_node(const float4* __restrict__ x4,
                                              const uint2* __restrict__ xh,
                                              const int* __restrict__ aggi,
                                              const float* __restrict__ aggf,
                                              int useFix,
                                              const int* __restrict__ batch,
                                              const float* __restrict__ epsp,
                                              const float* __restrict__ ws,
                                              float* __restrict__ sums,
                                              float* __restrict__ cnt) {
    __shared__ float w1s4[4 * 516];      // 4 bank-offset replicas of w1 [j][c]
    __shared__ float b1s[128];
    __shared__ float b2s[64];
    __shared__ float h2t[8][16][68];     // per-wave h2 tile (slow path only)
    __shared__ int   bshW[256];

    int tid  = threadIdx.x;
    int wave = tid >> 6;
    int l    = tid & 63;
    int cl   = l & 15;
    int q8   = l >> 4;

    for (int i = tid; i < 2048; i += 512)
        w1s4[(i >> 9) * 516 + (i & 511)] = ws[WS_W1F + (i & 511)];
    if (tid < 128) b1s[tid] = ws[WS_B1F + tid];
    if (tid < 64)  b2s[tid] = ws[WS_B2F + tid];

    const unsigned short* w2t = (const unsigned short*)(ws + WS_W2F);
    short8 bfr[4][4];
    #pragma unroll
    for (int nt = 0; nt < 4; ++nt)
        #pragma unroll
        for (int ks = 0; ks < 4; ++ks)
            bfr[nt][ks] = *(const short8*)(w2t + (nt * 16 + cl) * 128 + ks * 32 + q8 * 8);

    __syncthreads();

    float ep = 1.0f + epsp[0];

    for (int half = 0; half < 2; ++half) {
        int tb16 = wave * 32 + half * 16;                 // tile base within block
        int node = blockIdx.x * 256 + tb16 + cl;
        bool valid = node < N_NODES;
        float4 xi = make_float4(0.f, 0.f, 0.f, 0.f);
        float4 ai = make_float4(0.f, 0.f, 0.f, 0.f);
        if (valid) {
            if (useFix) {
                uint2 p = xh[node];
                __half2 ab = *(__half2*)&p.x;
                __half2 cd = *(__half2*)&p.y;
                float2 f0 = __half22float2(ab);
                float2 f1 = __half22float2(cd);
                xi = make_float4(f0.x, f0.y, f1.x, f1.y);
                int4 av = ((const int4*)aggi)[node];
                ai = make_float4(av.x * FXI, av.y * FXI, av.z * FXI, av.w * FXI);
            } else {
                xi = x4[node];
                ai = ((const float4*)aggf)[node];
            }
        }
        int bn = valid ? batch[node] : -1;
        if (l < 16) bshW[tb16 + l] = bn;
        float hx = ep * xi.x + ai.x;
        float hy = ep * xi.y + ai.y;
        float hz = ep * xi.z + ai.z;
        float hw = ep * xi.w + ai.w;

        f32x4 acc[4];
        #pragma unroll
        for (int nt = 0; nt < 4; ++nt) acc[nt] = (f32x4){0.f, 0.f, 0.f, 0.f};

        #pragma unroll
        for (int ks = 0; ks < 4; ++ks) {
            float h1v[8];
            #pragma unroll
            for (int e = 0; e < 8; ++e) {
                int j = ks * 32 + q8 * 8 + e;
                const float4 wr = *(const float4*)&w1s4[q8 * 516 + j * 4];
                float h1 = fmaf(hx, wr.x, fmaf(hy, wr.y, fmaf(hz, wr.z, fmaf(hw, wr.w, b1s[j]))));
                h1v[e] = fmaxf(h1, 0.0f);
            }
            unsigned int aw[4];
            #pragma unroll
            for (int p2 = 0; p2 < 4; ++p2)
                asm("v_cvt_pk_bf16_f32 %0, %1, %2"
                    : "=v"(aw[p2]) : "v"(h1v[2 * p2]), "v"(h1v[2 * p2 + 1]));
            short8 afrag = *(short8*)aw;
            #pragma unroll
            for (int nt = 0; nt < 4; ++nt)
                acc[nt] = __builtin_amdgcn_mfma_f32_16x16x32_bf16(afrag, bfr[nt][ks], acc[nt], 0, 0, 0);
        }

        float h2v[4][4];
        #pragma unroll
        for (int nt = 0; nt < 4; ++nt) {
            float b2v = b2s[nt * 16 + cl];
            #pragma unroll
            for (int r = 0; r < 4; ++r)
                h2v[nt][r] = fmaxf(acc[nt][r] + b2v, 0.0f);
        }

        int firstb = __shfl(bn, 0);
        bool uni = __all(bn == firstb) && (firstb >= 0);
        if (uni) {
            float s[4];
            #pragma unroll
            for (int nt = 0; nt < 4; ++nt) {
                float v = h2v[nt][0] + h2v[nt][1] + h2v[nt][2] + h2v[nt][3];
                v += __shfl_xor(v, 16);
                v += __shfl_xor(v, 32);
                s[nt] = v;
            }
            if (l < 16) {
                #pragma unroll
                for (int nt = 0; nt < 4; ++nt)
                    atomicAdd(&sums[firstb * 64 + nt * 16 + l], s[nt]);
            }
            if (l == 0) atomicAdd(&cnt[firstb], 16.0f);
        } else {
            #pragma unroll
            for (int nt = 0; nt < 4; ++nt)
                #pragma unroll
                for (int r = 0; r < 4; ++r)
                    h2t[wave][q8 * 4 + r][nt * 16 + cl] = h2v[nt][r];
            int kout = l;   // 0..63
            float a = 0.f, c = 0.f;
            int cur = -1;
            for (int n = 0; n < 16; ++n) {
                int bn2 = bshW[tb16 + n];
                if (bn2 != cur) {
                    if (cur >= 0) {
                        atomicAdd(&sums[cur * 64 + kout], a);
                        if (l == 0) atomicAdd(&cnt[cur], c);
                    }
                    a = 0.f; c = 0.f; cur = bn2;
                }
                if (bn2 >= 0) { a += h2t[wave][n][kout]; c += 1.f; }
            }
            if (cur >= 0) {
                atomicAdd(&sums[cur * 64 + kout], a);
                if (l == 0) atomicAdd(&cnt[cur], c);
            }
        }
    }
}

// ---------------- head ----------------
__global__ __launch_bounds__(256) void k_head(const float* __restrict__ sums,
                                              const float* __restrict__ cnt,
                                              const float* __restrict__ w3,
                                              const float* __restrict__ b3,
                                              float* __restrict__ out) {
    int g = blockIdx.x * 256 + threadIdx.x;
    if (g >= N_GRAPHS) return;
    float ic = 1.0f / fmaxf(cnt[g], 1.0f);
    float l0 = b3[0], l1 = b3[1];
    #pragma unroll 8
    for (int k = 0; k < 64; ++k) {
        float p = sums[g * 64 + k] * ic;
        l0 = fmaf(p, w3[k * 2 + 0], l0);
        l1 = fmaf(p, w3[k * 2 + 1], l1);
    }
    float m = fmaxf(l0, l1);
    float lse = m + logf(expf(l0 - m) + expf(l1 - m));
    out[g * 2 + 0] = l0 - lse;
    out[g * 2 + 1] = l1 - lse;
}

extern "C" void kernel_launch(void* const* d_in, const int* in_sizes, int n_in,
                              void* d_out, int out_size, void* d_ws, size_t ws_size,
                              hipStream_t stream) {
    const float* x   = (const float*)d_in[0];
    const float* eps = (const float*)d_in[1];
    const float* w1  = (const float*)d_in[2];
    const float* b1  = (const float*)d_in[3];
    const float* g1  = (const float*)d_in[4];
    const float* be1 = (const float*)d_in[5];
    const float* m1  = (const float*)d_in[6];
    const float* v1  = (const float*)d_in[7];
    const float* w2  = (const float*)d_in[8];
    const float* b2  = (const float*)d_in[9];
    const float* g2  = (const float*)d_in[10];
    const float* be2 = (const float*)d_in[11];
    const float* m2  = (const float*)d_in[12];
    const float* v2  = (const float*)d_in[13];
    const float* w3  = (const float*)d_in[14];
    const float* b3  = (const float*)d_in[15];
    const int*   ei  = (const int*)d_in[16];
    const int*   batch = (const int*)d_in[17];

    float* ws = (float*)d_ws;
    int*   wsi = (int*)d_ws;

    k_prep<<<1, 128, 0, stream>>>(w1, b1, g1, be1, m1, v1, w2, b2, g2, be2, m2, v2, ws);

    if (ws_size >= (size_t)WS_TOTAL_ELEMS * 4) {
        // zero only sums + cnt (agg fully stored by e4)
        (void)hipMemsetAsync(ws + WS_SUMS, 0, (size_t)325000 * sizeof(float), stream);

        k_e1_hist<<<NCH, 256, 0, stream>>>(ei, wsi + WS_HIST);
        k_e2a_scan<<<NBIN, 256, 0, stream>>>(wsi + WS_HIST, wsi + WS_BTOT);
        k_e2b_scan<<<1, NBIN, 0, stream>>>(wsi + WS_BTOT, wsi + WS_BSTART);
        k_e3_sort<<<NCH, E3T, 0, stream>>>(ei, wsi + WS_HIST, wsi + WS_BTOT,
                                           wsi + WS_BSTART,
                                           (unsigned int*)(wsi + WS_CSR));
        // hist is dead now -> overlay fp16 x table
        k_xhalf<<<(N_NODES + 255) / 256, 256, 0, stream>>>((const float4*)x,
                                                           (uint2*)(wsi + WS_XH));
        k_e4_agg<<<NBIN, 1024, 0, stream>>>((const unsigned int*)(wsi + WS_CSR),
                                            wsi + WS_BSTART,
                                            (const uint2*)(wsi + WS_XH),
                                            wsi + WS_AGG);
        k_node<<<(N_NODES + 255) / 256, 512, 0, stream>>>(
            (const float4*)x, (const uint2*)(wsi + WS_XH), wsi + WS_AGG,
            (const float*)nullptr, 1, batch, eps, ws,
            ws + WS_SUMS, ws + WS_CNT);
    } else {
        // fallback: global-atomic scatter into float agg placed in CSR region
        (void)hipMemsetAsync(ws + WS_SUMS, 0, (size_t)325000 * sizeof(float), stream);
        (void)hipMemsetAsync(ws + WS_CSR, 0, (size_t)2000000 * sizeof(float), stream);
        k_edge<<<(N_EDGES + 255) / 256, 256, 0, stream>>>(ei, (const float4*)x,
                                                          ws + WS_CSR);
        k_node<<<(N_NODES + 255) / 256, 512, 0, stream>>>(
            (const float4*)x, (const uint2*)nullptr, (const int*)nullptr,
            ws + WS_CSR, 0, batch, eps, ws,
            ws + WS_SUMS, ws + WS_CNT);
    }

    k_head<<<(N_GRAPHS + 255) / 256, 256, 0, stream>>>(
        ws + WS_SUMS, ws + WS_CNT, w3, b3, (float*)d_out);
}